// Round 4
// baseline (80.935 us; speedup 1.0000x reference)
//
#include <hip/hip_runtime.h>
#include <math.h>

#define BATCH 8
#define CIN   128
#define COUT  128
#define HH    64
#define WW    64
#define OC    27        // 3*K2
#define KDIM  1152      // CIN*9

typedef unsigned short u16;
typedef unsigned int   u32;
typedef __attribute__((ext_vector_type(8))) short bf16x8;
typedef __attribute__((ext_vector_type(4))) float f32x4;

__device__ __forceinline__ float b2f(u16 u) {
    return __uint_as_float((u32)u << 16);
}
__device__ __forceinline__ u16 f2b(float f) {   // RTNE
    u32 u = __float_as_uint(f);
    return (u16)((u + 0x7fffu + ((u >> 16) & 1u)) >> 16);
}
__device__ __forceinline__ float blo(u32 u) { return __uint_as_float(u << 16); }
__device__ __forceinline__ float bhi(u32 u) { return __uint_as_float(u & 0xffff0000u); }
__device__ __forceinline__ u32 cvtpk(float lo, float hi) {
    u32 r;
    asm("v_cvt_pk_bf16_f32 %0, %1, %2" : "=v"(r) : "v"(lo), "v"(hi));
    return r;
}

// ---------------- K_t: x NCHW f32 -> NHWC bf16 (hi) + residual (lo) ----------------
__global__ __launch_bounds__(256) void k_transpose_x(const float* __restrict__ x,
                                                     u16* __restrict__ xtb,
                                                     u16* __restrict__ xlo) {
    __shared__ float tile[64][65];
    int bid = blockIdx.x;              // 8 b * 2 cblk * 64 hwblk = 1024
    int b   = bid >> 7;
    int c0  = ((bid >> 6) & 1) << 6;
    int hw0 = (bid & 63) << 6;
    int t   = threadIdx.x;
    int ln  = t & 63;
    int cq  = t >> 6;                  // 0..3
#pragma unroll
    for (int r = 0; r < 16; ++r) {
        int c_l = cq * 16 + r;
        tile[c_l][ln] = x[(((size_t)(b * CIN + c0 + c_l)) << 12) + hw0 + ln];
    }
    __syncthreads();
#pragma unroll
    for (int r = 0; r < 16; ++r) {
        int hw_w = cq * 16 + r;
        float v = tile[ln][hw_w];
        u16 hi = f2b(v);
        u16 lo = f2b(v - b2f(hi));
        size_t dst = ((size_t)(b << 12) + hw0 + hw_w) * 128 + c0 + ln;
        xtb[dst] = hi;
        xlo[dst] = lo;
    }
}

// ---------------- K_w: pack main weight into B-fragment order, bf16 ----------------
__global__ __launch_bounds__(256) void k_pack_w(const float* __restrict__ weight,
                                                u16* __restrict__ wbf) {
    int tid = blockIdx.x * 256 + threadIdx.x;    // 576 blocks, exact
    int j  = tid & 7;
    int l  = (tid >> 3) & 63;
    int ni = (tid >> 9) & 7;
    int s  = (tid >> 12) & 3;
    int t9 = tid >> 14;
    int co = ni * 16 + (l & 15);
    int ci = s * 32 + ((l >> 4) << 3) + j;
    wbf[tid] = f2b(weight[co * KDIM + ci * 9 + t9]);
}

// ---------------- K_wo: pack offset-conv weight, hi/lo split, co padded 27->32 ----
__global__ __launch_bounds__(256) void k_pack_woff(const float* __restrict__ w_off,
                                                   u16* __restrict__ wop) {
    int tid = blockIdx.x * 256 + threadIdx.x;    // 288 blocks, exact (73728)
    int j   = tid & 7;
    int l   = (tid >> 3) & 63;
    int ni  = (tid >> 9) & 1;
    int sg  = (tid >> 10) & 3;
    int rest = tid >> 12;
    int t9  = rest % 9;
    int split = rest / 9;
    int co = ni * 16 + (l & 15);
    int ci = sg * 32 + ((l >> 4) << 3) + j;
    float val = (co < OC) ? w_off[co * KDIM + ci * 9 + t9] : 0.f;
    u16 hi = f2b(val);
    u16 lo = f2b(val - b2f(hi));
    wop[tid] = split ? lo : hi;
}

// ---------------- K1: offset conv via MFMA (implicit GEMM, hi/lo split) ----------
// block = 64 px (full row) x 32 co, 4 waves (16 px each). 512 blocks.
__global__ __launch_bounds__(256) void k_off_mfma(const u16* __restrict__ xtb,
                                                  const u16* __restrict__ xlo,
                                                  const u16* __restrict__ wop,
                                                  const float* __restrict__ b_off,
                                                  float* __restrict__ om) {
    __shared__ __align__(16) u16 Xh[3 * 66 * 64];   // 25344 B
    __shared__ __align__(16) u16 Xl[3 * 66 * 64];

    const int t    = threadIdx.x;
    const int b    = blockIdx.x >> 6;
    const int h    = blockIdx.x & 63;
    const int l    = t & 63;
    const int wv   = t >> 6;            // 0..3 -> px group
    const int row0 = l & 15;
    const int kg   = l >> 4;

    f32x4 acc0 = {0.f, 0.f, 0.f, 0.f};   // co 0..15
    f32x4 acc1 = {0.f, 0.f, 0.f, 0.f};   // co 16..31

    for (int half = 0; half < 2; ++half) {
        __syncthreads();
        // ---- stage 3 rows x 66 px x 64 ci (hi+lo), XOR-swizzled ----
        for (int i = t; i < 3 * 66 * 8; i += 256) {
            int row = i / 528;
            int rem = i - row * 528;
            int p = rem >> 3, q = rem & 7;
            int grow = h - 1 + row;
            int gw   = p - 1;
            int dstb = ((row * 66 + p) << 7) + ((q ^ (p & 7)) << 4);
            bf16x8 vh = {0, 0, 0, 0, 0, 0, 0, 0};
            bf16x8 vl = {0, 0, 0, 0, 0, 0, 0, 0};
            if ((unsigned)grow < 64u && (unsigned)gw < 64u) {
                size_t src = ((((size_t)b << 12) + (grow << 6) + gw) << 7) + half * 64 + q * 8;
                vh = *(const bf16x8*)(xtb + src);
                vl = *(const bf16x8*)(xlo + src);
            }
            *(bf16x8*)((char*)Xh + dstb) = vh;
            *(bf16x8*)((char*)Xl + dstb) = vl;
        }
        __syncthreads();

        for (int tap = 0; tap < 9; ++tap) {
            int kh = tap / 3, kw = tap - kh * 3;
            int p = wv * 16 + row0 + kw;           // 0..65
            int rowb = (kh * 66 + p) << 7;
#pragma unroll
            for (int s = 0; s < 2; ++s) {
                int q = s * 4 + kg;
                int off = rowb + ((q ^ (p & 7)) << 4);
                bf16x8 ah = *(const bf16x8*)((const char*)Xh + off);
                bf16x8 al = *(const bf16x8*)((const char*)Xl + off);
                int sg = half * 2 + s;
                const u16* B = wop + (((tap * 4 + sg)) << 10) + (l << 3);
                bf16x8 bh0 = *(const bf16x8*)(B);
                bf16x8 bh1 = *(const bf16x8*)(B + 512);
                bf16x8 bl0 = *(const bf16x8*)(B + 36864);
                bf16x8 bl1 = *(const bf16x8*)(B + 36864 + 512);
                acc0 = __builtin_amdgcn_mfma_f32_16x16x32_bf16(ah, bh0, acc0, 0, 0, 0);
                acc1 = __builtin_amdgcn_mfma_f32_16x16x32_bf16(ah, bh1, acc1, 0, 0, 0);
                acc0 = __builtin_amdgcn_mfma_f32_16x16x32_bf16(al, bh0, acc0, 0, 0, 0);
                acc1 = __builtin_amdgcn_mfma_f32_16x16x32_bf16(al, bh1, acc1, 0, 0, 0);
                acc0 = __builtin_amdgcn_mfma_f32_16x16x32_bf16(ah, bl0, acc0, 0, 0, 0);
                acc1 = __builtin_amdgcn_mfma_f32_16x16x32_bf16(ah, bl1, acc1, 0, 0, 0);
            }
        }
    }

    // ---- epilogue ----
    int wpx = wv * 16 + (kg << 2);
    int co0 = row0;
    {
        float bb = b_off[co0];
        float4 r = make_float4(acc0.x + bb, acc0.y + bb, acc0.z + bb, acc0.w + bb);
        *(float4*)(om + (((size_t)(b * OC + co0)) << 12) + (h << 6) + wpx) = r;
    }
    int co1 = co0 + 16;
    if (co1 < OC) {
        float bb = b_off[co1];
        float4 r = make_float4(acc1.x + bb, acc1.y + bb, acc1.z + bb, acc1.w + bb);
        if (co1 >= 18) {
            r.x = 1.f / (1.f + expf(-r.x));
            r.y = 1.f / (1.f + expf(-r.y));
            r.z = 1.f / (1.f + expf(-r.z));
            r.w = 1.f / (1.f + expf(-r.w));
        }
        *(float4*)(om + (((size_t)(b * OC + co1)) << 12) + (h << 6) + wpx) = r;
    }
}

// ---------------- K2: bilinear sampling (NHWC bf16) + MFMA GEMM ----------------
// block = 64 px (full row) x 128 cout, 4 waves co-split 32 each. 512 blocks.
__global__ __launch_bounds__(256) void k_sample_gemm(const u16* __restrict__ xtb,
                                                     const float* __restrict__ om,
                                                     const u16* __restrict__ wbf,
                                                     const float* __restrict__ bias,
                                                     float* __restrict__ out) {
    __shared__ __align__(16) u16 Abuf[2][64 * 128];   // 32 KB, [buf][px][ch] swizzled
    __shared__ float w4[576][4];
    __shared__ int y0c[576], x0c[576], y1c[576], x1c[576];

    const int t = threadIdx.x;
    const int b = blockIdx.x >> 6;
    const int h = blockIdx.x & 63;

    // ---- phase 0: bilinear params for 64 px x 9 taps ----
    for (int i = t; i < 576; i += 256) {
        int p  = i / 9;
        int tt = i - p * 9;
        const float* ob = om + ((size_t)b * OC) * 4096 + (h << 6) + p;
        float dy = ob[(size_t)tt << 12];
        float dx = ob[(size_t)(9 + tt) << 12];
        float m  = ob[(size_t)(18 + tt) << 12];   // sigmoided in K1
        float py = dy + (float)(h - 1 + tt / 3);
        float px = dx + (float)(p - 1 + tt % 3);
        float y0f = floorf(py), x0f = floorf(px);
        float wy = py - y0f, wx = px - x0f;
        int y0 = (int)y0f, x0 = (int)x0f;
        int y1 = y0 + 1,   x1 = x0 + 1;
        float vy0 = ((unsigned)y0 < 64u) ? 1.f : 0.f;
        float vy1 = ((unsigned)y1 < 64u) ? 1.f : 0.f;
        float vx0 = ((unsigned)x0 < 64u) ? 1.f : 0.f;
        float vx1 = ((unsigned)x1 < 64u) ? 1.f : 0.f;
        w4[i][0] = (1.f - wy) * (1.f - wx) * m * vy0 * vx0;
        w4[i][1] = (1.f - wy) * wx         * m * vy0 * vx1;
        w4[i][2] = wy         * (1.f - wx) * m * vy1 * vx0;
        w4[i][3] = wy         * wx         * m * vy1 * vx1;
        y0c[i] = min(max(y0, 0), 63);
        y1c[i] = min(max(y1, 0), 63);
        x0c[i] = min(max(x0, 0), 63);
        x1c[i] = min(max(x1, 0), 63);
    }
    __syncthreads();

    f32x4 acc[4][2];
#pragma unroll
    for (int pt = 0; pt < 4; ++pt)
#pragma unroll
        for (int nt = 0; nt < 2; ++nt) acc[pt][nt] = (f32x4){0.f, 0.f, 0.f, 0.f};

    const int l    = t & 63;
    const int wv   = t >> 6;
    const int row0 = l & 15;
    const int kg   = l >> 4;

    const int sp = t >> 2;          // sampling: pixel 0..63
    const int sc = t & 3;           // sampling: 16B sub-chunk
    const u16* xb = xtb + ((size_t)b << 19);

    auto sample = [&](int tt, int buf) {
        int pi = sp * 9 + tt;
        int o00 = ((y0c[pi] << 6) | x0c[pi]) << 7;
        int o01 = ((y0c[pi] << 6) | x1c[pi]) << 7;
        int o10 = ((y1c[pi] << 6) | x0c[pi]) << 7;
        int o11 = ((y1c[pi] << 6) | x1c[pi]) << 7;
        float4 W = *(const float4*)(&w4[pi][0]);
        u16* dst = &Abuf[buf][0];
#pragma unroll
        for (int k = 0; k < 4; ++k) {
            int ch = k * 32 + sc * 8;            // 4-lane groups load 64B contiguous
            uint4 a00 = *(const uint4*)(xb + o00 + ch);
            uint4 a01 = *(const uint4*)(xb + o01 + ch);
            uint4 a10 = *(const uint4*)(xb + o10 + ch);
            uint4 a11 = *(const uint4*)(xb + o11 + ch);
            uint4 ow;
            {
                float e0 = W.x * blo(a00.x) + W.y * blo(a01.x) + W.z * blo(a10.x) + W.w * blo(a11.x);
                float e1 = W.x * bhi(a00.x) + W.y * bhi(a01.x) + W.z * bhi(a10.x) + W.w * bhi(a11.x);
                ow.x = cvtpk(e0, e1);
            }
            {
                float e0 = W.x * blo(a00.y) + W.y * blo(a01.y) + W.z * blo(a10.y) + W.w * blo(a11.y);
                float e1 = W.x * bhi(a00.y) + W.y * bhi(a01.y) + W.z * bhi(a10.y) + W.w * bhi(a11.y);
                ow.y = cvtpk(e0, e1);
            }
            {
                float e0 = W.x * blo(a00.z) + W.y * blo(a01.z) + W.z * blo(a10.z) + W.w * blo(a11.z);
                float e1 = W.x * bhi(a00.z) + W.y * bhi(a01.z) + W.z * bhi(a10.z) + W.w * bhi(a11.z);
                ow.z = cvtpk(e0, e1);
            }
            {
                float e0 = W.x * blo(a00.w) + W.y * blo(a01.w) + W.z * blo(a10.w) + W.w * blo(a11.w);
                float e1 = W.x * bhi(a00.w) + W.y * bhi(a01.w) + W.z * bhi(a10.w) + W.w * bhi(a11.w);
                ow.w = cvtpk(e0, e1);
            }
            int q16 = k * 4 + sc;
            *(uint4*)((char*)dst + (sp << 8) + ((q16 ^ (sp & 7)) << 4)) = ow;
        }
    };

    auto domfma = [&](int t9, int buf) {
        const char* Ab = (const char*)&Abuf[buf][0];
#pragma unroll
        for (int s = 0; s < 4; ++s) {
            int q = s * 4 + kg;
            int sw = (q ^ (row0 & 7)) << 4;
            bf16x8 a[4];
#pragma unroll
            for (int pt = 0; pt < 4; ++pt)
                a[pt] = *(const bf16x8*)(Ab + ((pt * 16 + row0) << 8) + sw);
            const u16* B = wbf + ((size_t)t9 << 14) + (s << 12) + (wv << 10) + (l << 3);
            bf16x8 b0 = *(const bf16x8*)(B);
            bf16x8 b1 = *(const bf16x8*)(B + 512);
#pragma unroll
            for (int pt = 0; pt < 4; ++pt) {
                acc[pt][0] = __builtin_amdgcn_mfma_f32_16x16x32_bf16(a[pt], b0, acc[pt][0], 0, 0, 0);
                acc[pt][1] = __builtin_amdgcn_mfma_f32_16x16x32_bf16(a[pt], b1, acc[pt][1], 0, 0, 0);
            }
        }
    };

    sample(0, 0);
    __syncthreads();
    for (int tt = 0; tt < 9; ++tt) {
        if (tt < 8) sample(tt + 1, (tt + 1) & 1);
        domfma(tt, tt & 1);
        __syncthreads();
    }

    // ---- epilogue: acc -> LDS (swizzled f32 [co][px]) -> coalesced global ----
    {
        float* outs = (float*)&Abuf[0][0];    // 128co x 64px f32 = 32 KB
#pragma unroll
        for (int pt = 0; pt < 4; ++pt)
#pragma unroll
            for (int nt = 0; nt < 2; ++nt) {
                int co  = wv * 32 + nt * 16 + row0;
                int pxq = pt * 4 + kg;
                *(f32x4*)((char*)outs + (co << 8) + ((pxq ^ (co & 7)) << 4)) = acc[pt][nt];
            }
    }
    __syncthreads();
    {
        const float* outs = (const float*)&Abuf[0][0];
        int co = t >> 1, ph = t & 1;
        float bb = bias[co];
        float* og = out + (((size_t)(b * COUT + co)) << 12) + (h << 6) + ph * 32;
#pragma unroll
        for (int j = 0; j < 8; ++j) {
            int pxq = ph * 8 + j;
            f32x4 v = *(const f32x4*)((const char*)outs + (co << 8) + ((pxq ^ (co & 7)) << 4));
            float4 r = make_float4(v.x + bb, v.y + bb, v.z + bb, v.w + bb);
            *reinterpret_cast<float4*>(og + j * 4) = r;
        }
    }
}

// ---------------- host ----------------
extern "C" void kernel_launch(void* const* d_in, const int* in_sizes, int n_in,
                              void* d_out, int out_size, void* d_ws, size_t ws_size,
                              hipStream_t stream) {
    const float* x      = (const float*)d_in[0];
    const float* w_off  = (const float*)d_in[1];
    const float* b_off  = (const float*)d_in[2];
    const float* weight = (const float*)d_in[3];
    const float* bias   = (const float*)d_in[4];
    float* out = (float*)d_out;

    float* om  = (float*)d_ws;                        // 884736 f32
    u16*   xtb = (u16*)(om + 884736);                 // 4194304 u16 (NHWC bf16 hi)
    u16*   wbf = xtb + 4194304;                       // 147456 u16 (main B-frags)
    u16*   wop = wbf + 147456;                        // 73728 u16 (offset B-frags hi/lo)
    u16*   xlo = (u16*)d_out;                         // 8 MB scratch inside out (16.7 MB);
                                                      // consumed before k_sample_gemm writes out

    k_pack_w<<<576, 256, 0, stream>>>(weight, wbf);
    k_pack_woff<<<288, 256, 0, stream>>>(w_off, wop);
    k_transpose_x<<<1024, 256, 0, stream>>>(x, xtb, xlo);
    k_off_mfma<<<512, 256, 0, stream>>>(xtb, xlo, wop, b_off, om);
    k_sample_gemm<<<512, 256, 0, stream>>>(xtb, om, wbf, bias, out);
}